// Round 12
// baseline (55.741 us; speedup 1.0000x reference)
//
#include <hip/hip_runtime.h>
#include <math.h>

// Lee Oscillator: per-element 100-step chaotic recurrence, time-max-pooled.
// Bitwise-matches jax/XLA-CPU f32 semantics (PROVEN: rounds 6-11 absmax=0.0).
// The arithmetic (xla_tanhf/xla_expf/fusion pattern) must not change.
//
// Round-12: k_process was chain-latency-bound (VALUBusy 45% @ 2.6 waves/SIMD;
// two serialized IEEE divides + 13-deep FMA chain per step). Split E/I across
// LANE PAIRS: even lane runs the E-tanh, odd lane the I-tanh, one v_mov_dpp
// quad_perm swap (pure bit move) exchanges results per step. Doubles waves
// (5.3/SIMD) and halves the per-step chain (one divide). All selected args
// use the exact verified op pattern; DPP/selects are bit moves -> bitwise.

#define N_STEPS 100

typedef float v2f __attribute__((ext_vector_type(2)));
__device__ __forceinline__ v2f splat2(float s){ v2f v; v.x = s; v.y = s; return v; }

// (a1,a2,a3,a4,b1,b2,b3,b4,xi_E,xi_I,mu,e,k) for oscillator types 1..8 (f32)
__constant__ float PAR[8][13] = {
    { 0.0f,  5.0f,  5.0f,  1.0f,  0.0f, -1.0f,  1.0f,  0.0f, 0.0f, 0.0f, 5.0f, 0.001f, 500.0f},
    { 0.5f,  0.55f, 0.55f, -0.5f,  0.5f, -0.55f, -0.55f, -0.5f, 0.0f, 0.0f, 1.0f, 0.001f, 50.0f},
    { 0.5f,  0.6f,  0.55f,  0.5f, -0.5f, -0.6f,  -0.55f,  0.5f, 0.0f, 0.0f, 1.0f, 0.001f, 50.0f},
    {-0.5f,  0.55f, 0.55f, -0.5f, -0.5f, -0.55f, -0.55f,  0.5f, 0.0f, 0.0f, 1.0f, 0.001f, 50.0f},
    {-0.9f,  0.9f,  0.9f,  -0.9f,  0.9f, -0.9f,  -0.9f,   0.9f, 0.0f, 0.0f, 1.0f, 0.001f, 50.0f},
    {-0.9f,  0.9f,  0.9f,  -0.9f,  0.9f, -0.9f,  -0.9f,   0.9f, 0.0f, 0.0f, 1.0f, 0.001f, 300.0f},
    {-5.0f,  5.0f,  5.0f,  -5.0f,  1.0f, -1.0f,  -1.0f,   1.0f, 0.0f, 0.0f, 1.0f, 0.001f, 50.0f},
    {-5.0f,  5.0f,  5.0f,  -5.0f,  1.0f, -1.0f,  -1.0f,   1.0f, 0.0f, 0.0f, 1.0f, 0.001f, 300.0f},
};

// XLA CPU f32 tanh — scalar form. [bitwise-verified rounds 6-11]
__device__ __forceinline__ float xla_tanhf(float x) {
#pragma clang fp contract(off)
    float ax = fabsf(x);
    float xc = fminf(fmaxf(x, -7.99881172180175781f), 7.99881172180175781f);
    float x2 = xc * xc;
    float p = -2.76076847742355e-16f;
    p = fmaf(p, x2, 2.00018790482477e-13f);
    p = fmaf(p, x2, -8.60467152213735e-11f);
    p = fmaf(p, x2, 5.12229709037114e-08f);
    p = fmaf(p, x2, 1.48572235717979e-05f);
    p = fmaf(p, x2, 6.37261928875436e-04f);
    p = fmaf(p, x2, 4.89352455891786e-03f);
    float num = xc * p;
    float q = 1.19825839466702e-06f;
    q = fmaf(q, x2, 1.18534705686654e-04f);
    q = fmaf(q, x2, 2.26843463243900e-03f);
    q = fmaf(q, x2, 4.89352518554385e-03f);
    float r = num / q;                       // IEEE f32 divide
    return (ax < 0.0004f) ? x : r;
}

// Packed 2-wide tanh: SAME per-component IEEE ops. [bitwise-verified 8-11]
__device__ __forceinline__ v2f xla_tanh2(v2f x) {
#pragma clang fp contract(off)
    const float C = 7.99881172180175781f;
    v2f xc = __builtin_elementwise_min(__builtin_elementwise_max(x, splat2(-C)), splat2(C));
    v2f x2 = xc * xc;
    v2f p = splat2(-2.76076847742355e-16f);
    p = __builtin_elementwise_fma(p, x2, splat2(2.00018790482477e-13f));
    p = __builtin_elementwise_fma(p, x2, splat2(-8.60467152213735e-11f));
    p = __builtin_elementwise_fma(p, x2, splat2(5.12229709037114e-08f));
    p = __builtin_elementwise_fma(p, x2, splat2(1.48572235717979e-05f));
    p = __builtin_elementwise_fma(p, x2, splat2(6.37261928875436e-04f));
    p = __builtin_elementwise_fma(p, x2, splat2(4.89352455891786e-03f));
    v2f num = xc * p;
    v2f q = splat2(1.19825839466702e-06f);
    q = __builtin_elementwise_fma(q, x2, splat2(1.18534705686654e-04f));
    q = __builtin_elementwise_fma(q, x2, splat2(2.26843463243900e-03f));
    q = __builtin_elementwise_fma(q, x2, splat2(4.89352518554385e-03f));
    float rE = num.x / q.x;                  // IEEE f32 divides
    float rI = num.y / q.y;
    v2f r;
    r.x = (fabsf(x.x) < 0.0004f) ? x.x : rE;
    r.y = (fabsf(x.y) < 0.0004f) ? x.y : rI;
    return r;
}

// XLA CPU f32 exp (Cephes/Eigen pexp), FMA-contracted. [bitwise-verified]
__device__ __forceinline__ float xla_expf(float x) {
#pragma clang fp contract(off)
    float xc = fminf(fmaxf(x, -88.3762626647949f), 88.3762626647950f);
    float fx = floorf(fmaf(xc, 1.44269504088896341f, 0.5f));
    float r = fmaf(fx, -0.693359375f, xc);
    r = fmaf(fx, 2.12194440e-4f, r);
    float r2 = r * r;
    float y = 1.9875691500e-4f;
    y = fmaf(y, r, 1.3981999507e-3f);
    y = fmaf(y, r, 8.3334519073e-3f);
    y = fmaf(y, r, 4.1665795894e-2f);
    y = fmaf(y, r, 1.6666665459e-1f);
    y = fmaf(y, r, 5.0000001201e-1f);
    y = fmaf(y, r2, r);
    y = y + 1.0f;
    int n2 = (int)fx;
    float p2n = __int_as_float((n2 + 127) << 23);   // n==-127 -> +0.0
    return y * p2n;
}

// Shared per-element preamble (bitwise-identical everywhere).
__device__ __forceinline__ void preamble(float xv, const float* p,
                                         float& sim0, float& damp, float& omega) {
#pragma clang fp contract(off)
    float mu = p[10], e = p[11], k = p[12];
    float sgn  = (xv > 0.0f) ? 1.0f : ((xv < 0.0f) ? -1.0f : 0.0f);
    sim0 = fmaf(e, sgn, xv);                  // fadd(x, fmul(e,sgn)) fused
    float targ = (-k * sim0) * sim0;          // two plain muls
    damp  = xla_expf(targ);
    omega = xla_tanhf(mu * sim0);
}

// Full predicate (t != 1 and monolithic fallback). PROVEN lemma (round 9):
// 2*damp < |omega|*2^-26 with |D|<2 => fma(D,damp,omega)==omega every step.
__device__ __forceinline__ bool fast_omega(float damp, float omega) {
    return (2.0f * damp) < (fabsf(omega) * 0x1p-26f);
}

// t==1 cheap classification: slow iff |sim0| <= 0.21. PROVEN subset of the
// predicate above (22x margin at the boundary, grows like e^{500(s^2-0.0441)}).
// Slow-side routing is always correctness-neutral (loop returns omega).
__device__ __forceinline__ bool slow_t1(float xv, float e) {
#pragma clang fp contract(off)
    float sgn  = (xv > 0.0f) ? 1.0f : ((xv < 0.0f) ? -1.0f : 0.0f);
    float sim0 = fmaf(e, sgn, xv);
    return fabsf(sim0) <= 0.21f;
}

// 100-step loop, type-1, single element (monolithic fallback). [verified]
__device__ __forceinline__ float loop_t1(float sim0, float damp, float omega) {
#pragma clang fp contract(off)
    float E = 0.2f, I = 0.0f;
    float Dmax = -INFINITY;
    for (int s = 0; s < N_STEPS; ++s) {
        float tE = 5.0f * E;
        v2f mulc; mulc.x = -5.0f; mulc.y = -1.0f;
        v2f iv   = splat2(I);
        v2f addv; addv.x = tE;    addv.y = E;
        v2f u = __builtin_elementwise_fma(mulc, iv, addv);
        float sE = u.x + sim0;
        v2f pre; pre.x = sE; pre.y = u.y;
        v2f args = splat2(5.0f) * pre;
        v2f t = xla_tanh2(args);
        float D = t.x - t.y;
        Dmax = fmaxf(Dmax, D);
        E = t.x; I = t.y;
    }
    return fmaf(Dmax, damp, omega);
}

// Generic-type loop (L feedback), proven scalar form.
__device__ __forceinline__ float loop_gen(const float* p, float sim0,
                                          float damp, float omega) {
#pragma clang fp contract(off)
    float a1 = p[0], a2 = p[1], a3 = p[2], a4 = p[3];
    float b1 = p[4], b2 = p[5], b3 = p[6], b4 = p[7];
    float xiE = p[8], xiI = p[9], mu = p[10];
    float nb2 = -b2;
    float E = 0.2f, I = 0.0f, L = 0.2f;
    float m = -INFINITY;
    for (int s = 0; s < N_STEPS; ++s) {
        float tE = a2 * E;
        float uE = fmaf(a1, L, tE);
        uE = fmaf(-a3, I, uE);
        uE = fmaf(a4, sim0, uE);
        uE = uE - xiE;
        float argE = mu * uE;
        float tI = nb2 * E;
        float uI = fmaf(b1, L, tI);
        uI = fmaf(-b3, I, uI);
        uI = fmaf(b4, sim0, uI);
        uI = uI - xiI;
        float argI = mu * uI;
        float E1 = xla_tanhf(argE);
        float I1 = xla_tanhf(argI);
        float d = E1 - I1;
        L = fmaf(d, damp, omega);
        E = E1; I = I1;
        m = fmaxf(m, L);
    }
    return m;
}

// Classification shared by k_count / k_fill (must agree EXACTLY).
__device__ __forceinline__ bool classify_slow(float xv, int t, const float* p) {
    if (t == 1) return slow_t1(xv, p[11]);
    float sim0, damp, omega;
    preamble(xv, p, sim0, damp, omega);
    return !fast_omega(damp, omega);
}

// ---------------- kernels ----------------

// 1) per-block slow-lane count (ballot + popc, no atomics)
__global__ __launch_bounds__(256)
void k_count(const float* __restrict__ x, const int* __restrict__ osc_type,
             unsigned* __restrict__ bcount, int n)
{
    __shared__ unsigned wc[4];
    int i = blockIdx.x * 256 + threadIdx.x;
    int t = *osc_type;
    const float* p = PAR[t - 1];
    bool slow = (i < n) && classify_slow(x[i], t, p);
    unsigned long long mask = __ballot(slow);
    int lane = threadIdx.x & 63, wid = threadIdx.x >> 6;
    if (lane == 0) wc[wid] = (unsigned)__popcll(mask);
    __syncthreads();
    if (threadIdx.x == 0) bcount[blockIdx.x] = wc[0] + wc[1] + wc[2] + wc[3];
}

// 2) fill: self-scan bcount for this block's base; fast lanes -> out=omega;
//    slow lanes -> wl[base + local prefix]; last block writes bcount[NB]=total.
__global__ __launch_bounds__(256)
void k_fill(const float* __restrict__ x, const int* __restrict__ osc_type,
            float* __restrict__ out, unsigned* __restrict__ bcount,
            unsigned* __restrict__ wl, int n, int NB)
{
#pragma clang fp contract(off)
    __shared__ unsigned sums[256];
    __shared__ unsigned woff[4];
    int tid = threadIdx.x;
    int bid = blockIdx.x;

    // self-scan: base = sum of bcount[0..bid)
    unsigned s = 0;
    for (int j = tid; j < bid; j += 256) s += bcount[j];
    sums[tid] = s;
    __syncthreads();
    for (int off = 128; off > 0; off >>= 1) {
        if (tid < off) sums[tid] += sums[tid + off];
        __syncthreads();
    }
    unsigned bbase = sums[0];

    int i = bid * 256 + tid;
    bool active = (i < n);
    int t = *osc_type;
    const float* p = PAR[t - 1];
    float xv = active ? x[i] : 1.0e9f;          // 1e9 -> fast (and inactive)
    bool slow = active && classify_slow(xv, t, p);
    if (active && !slow) {
        // omega, computed exactly as in preamble
        float mu = p[10], e = p[11];
        float sgn  = (xv > 0.0f) ? 1.0f : ((xv < 0.0f) ? -1.0f : 0.0f);
        float sim0 = fmaf(e, sgn, xv);
        out[i] = xla_tanhf(mu * sim0);
    }
    unsigned long long mask = __ballot(slow);
    int lane = tid & 63, wid = tid >> 6;
    if (lane == 0) woff[wid] = (unsigned)__popcll(mask);
    __syncthreads();
    if (slow) {
        unsigned base = bbase;
        for (int w = 0; w < wid; ++w) base += woff[w];
        base += (unsigned)__popcll(mask & ((1ull << lane) - 1ull));
        wl[base] = (unsigned)i;
    }
    if (tid == 0 && bid == NB - 1)
        bcount[NB] = bbase + woff[0] + woff[1] + woff[2] + woff[3];
}

// 3) dense worklist. t==1: TWO LANES PER ELEMENT — even lane computes the
//    E-tanh, odd lane the I-tanh; one v_mov_dpp quad_perm [1,0,3,2] swap
//    exchanges results each step. Doubles waves and halves the per-step
//    dependency chain (one IEEE-divide sequence instead of two serialized).
//    All ops/selected args follow the verified bit patterns exactly.
__global__ __launch_bounds__(128)
void k_process(const float* __restrict__ x, const int* __restrict__ osc_type,
               float* __restrict__ out, const unsigned* __restrict__ total_p,
               const unsigned* __restrict__ wl)
{
#pragma clang fp contract(off)
    unsigned total = *total_p;
    int t = *osc_type;
    const float* p = PAR[t - 1];
    if (t == 1) {
        bool odd = (threadIdx.x & 1u) != 0u;
        unsigned pairIdx = (blockIdx.x * 128u + threadIdx.x) >> 1;
        unsigned pstride = gridDim.x * 64u;          // pairs per grid pass
        for (; pairIdx < total; pairIdx += pstride) {
            int i = (int)wl[pairIdx];
            float sim0, damp, omega;
            preamble(x[i], p, sim0, damp, omega);    // same bits on both lanes
            float E = 0.2f, I = 0.0f;
            float Dmax = -INFINITY;
            for (int s = 0; s < N_STEPS; ++s) {
                // verified op patterns for both args (cheap; one tanh/lane)
                float tE = 5.0f * E;                 // round(5E)
                float uE = fmaf(-5.0f, I, tE);
                float sE = uE + sim0;                // plain fadd
                float aE = 5.0f * sE;
                float vI = E - I;                    // plain fsub
                float aI = 5.0f * vI;
                float arg = odd ? aI : aE;
                float tn  = xla_tanhf(arg);          // ONE divide per lane
                int   pi  = __builtin_amdgcn_mov_dpp(__float_as_int(tn),
                                                     0xB1, 0xF, 0xF, true);
                float tp  = __int_as_float(pi);      // partner's tanh (bit move)
                float E1 = odd ? tp : tn;
                float I1 = odd ? tn : tp;
                float D  = E1 - I1;                  // plain fsub
                Dmax = fmaxf(Dmax, D);
                E = E1; I = I1;
            }
            if (!odd) out[i] = fmaf(Dmax, damp, omega);
        }
    } else {
        unsigned tid = blockIdx.x * 128u + threadIdx.x;
        unsigned stride = gridDim.x * 128u;
        for (; tid < total; tid += stride) {
            int i = (int)wl[tid];
            float sim0, damp, omega;
            preamble(x[i], p, sim0, damp, omega);
            out[i] = loop_gen(p, sim0, damp, omega);
        }
    }
}

// Fallback: proven monolithic kernel (if ws too small).
__global__ __launch_bounds__(256)
void k_monolithic(const float* __restrict__ x, const int* __restrict__ osc_type,
                  float* __restrict__ out, int n)
{
#pragma clang fp contract(off)
    int i = blockIdx.x * 256 + threadIdx.x;
    if (i >= n) return;
    int t = *osc_type;
    const float* p = PAR[t - 1];
    float sim0, damp, omega;
    preamble(x[i], p, sim0, damp, omega);
    if (fast_omega(damp, omega)) { out[i] = omega; return; }
    out[i] = (t == 1) ? loop_t1(sim0, damp, omega)
                      : loop_gen(p, sim0, damp, omega);
}

extern "C" void kernel_launch(void* const* d_in, const int* in_sizes, int n_in,
                              void* d_out, int out_size, void* d_ws, size_t ws_size,
                              hipStream_t stream) {
    const float* x        = (const float*)d_in[0];
    const int*   osc_type = (const int*)d_in[1];
    float*       out      = (float*)d_out;
    int n = in_sizes[0];
    int NB = (n + 255) / 256;

    size_t needed = ((size_t)NB + 1 + (size_t)n) * sizeof(unsigned);
    if (ws_size >= needed) {
        unsigned* bcount = (unsigned*)d_ws;      // NB+1 entries ([NB] = total)
        unsigned* wl     = bcount + NB + 1;      // n entries
        k_count  <<<NB, 256, 0, stream>>>(x, osc_type, bcount, n);
        k_fill   <<<NB, 256, 0, stream>>>(x, osc_type, out, bcount, wl, n, NB);
        k_process<<<4096, 128, 0, stream>>>(x, osc_type, out, bcount + NB, wl);
    } else {
        k_monolithic<<<NB, 256, 0, stream>>>(x, osc_type, out, n);
    }
}

// Round 13
// 43.330 us; speedup vs baseline: 1.2864x; 1.2864x over previous
//
#include <hip/hip_runtime.h>
#include <math.h>

// Lee Oscillator: per-element 100-step chaotic recurrence, time-max-pooled.
// Bitwise-matches jax/XLA-CPU f32 semantics (PROVEN: rounds 6-12 absmax=0.0).
// The arithmetic (xla_tanhf/xla_expf/fusion pattern) must not change.
//
// Round-13: back to R11's 1-elem/lane k_process (best issue efficiency:
// 0.64 instr/elem-step vs pair-mode 1.1). Attack the real stall: the IEEE
// f32 '/' expansion (div_scale/div_fmas/div_fixup) serializes on VCC +
// denorm-mode s_setreg, so the two divides per step cannot overlap (R11
// VALUBusy 45%). Replace ONLY the hot-loop tanh division with a Markstein
// correctly-rounded sequence (rcp + 2 Newton + 2 exact-residual fixups):
// for q in [4.89e-3,0.94] and used |num| in [2e-6,0.95] this returns the
// EXACT IEEE quotient, with no VCC/mode traffic -> E/I chains interleave.
// A/B gate: if absmax != 0.0, revert div_exact -> '/' (single-function diff).

#define N_STEPS 100

typedef float v2f __attribute__((ext_vector_type(2)));
__device__ __forceinline__ v2f splat2(float s){ v2f v; v.x = s; v.y = s; return v; }

// (a1,a2,a3,a4,b1,b2,b3,b4,xi_E,xi_I,mu,e,k) for oscillator types 1..8 (f32)
__constant__ float PAR[8][13] = {
    { 0.0f,  5.0f,  5.0f,  1.0f,  0.0f, -1.0f,  1.0f,  0.0f, 0.0f, 0.0f, 5.0f, 0.001f, 500.0f},
    { 0.5f,  0.55f, 0.55f, -0.5f,  0.5f, -0.55f, -0.55f, -0.5f, 0.0f, 0.0f, 1.0f, 0.001f, 50.0f},
    { 0.5f,  0.6f,  0.55f,  0.5f, -0.5f, -0.6f,  -0.55f,  0.5f, 0.0f, 0.0f, 1.0f, 0.001f, 50.0f},
    {-0.5f,  0.55f, 0.55f, -0.5f, -0.5f, -0.55f, -0.55f,  0.5f, 0.0f, 0.0f, 1.0f, 0.001f, 50.0f},
    {-0.9f,  0.9f,  0.9f,  -0.9f,  0.9f, -0.9f,  -0.9f,   0.9f, 0.0f, 0.0f, 1.0f, 0.001f, 50.0f},
    {-0.9f,  0.9f,  0.9f,  -0.9f,  0.9f, -0.9f,  -0.9f,   0.9f, 0.0f, 0.0f, 1.0f, 0.001f, 300.0f},
    {-5.0f,  5.0f,  5.0f,  -5.0f,  1.0f, -1.0f,  -1.0f,   1.0f, 0.0f, 0.0f, 1.0f, 0.001f, 50.0f},
    {-5.0f,  5.0f,  5.0f,  -5.0f,  1.0f, -1.0f,  -1.0f,   1.0f, 0.0f, 0.0f, 1.0f, 0.001f, 300.0f},
};

// XLA CPU f32 tanh — scalar form with IEEE '/'. Used OUTSIDE the hot loop
// (preamble/omega/classification). [bitwise-verified rounds 6-12]
__device__ __forceinline__ float xla_tanhf(float x) {
#pragma clang fp contract(off)
    float ax = fabsf(x);
    float xc = fminf(fmaxf(x, -7.99881172180175781f), 7.99881172180175781f);
    float x2 = xc * xc;
    float p = -2.76076847742355e-16f;
    p = fmaf(p, x2, 2.00018790482477e-13f);
    p = fmaf(p, x2, -8.60467152213735e-11f);
    p = fmaf(p, x2, 5.12229709037114e-08f);
    p = fmaf(p, x2, 1.48572235717979e-05f);
    p = fmaf(p, x2, 6.37261928875436e-04f);
    p = fmaf(p, x2, 4.89352455891786e-03f);
    float num = xc * p;
    float q = 1.19825839466702e-06f;
    q = fmaf(q, x2, 1.18534705686654e-04f);
    q = fmaf(q, x2, 2.26843463243900e-03f);
    q = fmaf(q, x2, 4.89352518554385e-03f);
    float r = num / q;                       // IEEE f32 divide
    return (ax < 0.0004f) ? x : r;
}

// Correctly-rounded f32 divide for well-scaled normal operands
// (q in [4.89e-3, 0.94]; used |num| in [2e-6, 0.95]). Markstein:
// rcp (<=1ulp) + 2 Newton -> r within 0.5ulp of 1/q; residual
// rem = fma(-q,y,num) is EXACT (Sterbenz-type lemma for y within 1ulp);
// y' = fma(rem, r, y) is the round-to-nearest quotient == IEEE '/'.
// No VCC, no denorm-mode s_setreg -> two instances interleave freely.
__device__ __forceinline__ float div_exact(float a, float b) {
#pragma clang fp contract(off)
    float r = __builtin_amdgcn_rcpf(b);
    float e = fmaf(-b, r, 1.0f);
    r = fmaf(e, r, r);                        // Newton 1
    float e2 = fmaf(-b, r, 1.0f);
    r = fmaf(e2, r, r);                       // Newton 2
    float y = a * r;
    float rem = fmaf(-b, y, a);               // exact residual
    y = fmaf(rem, r, y);                      // fixup 1 (Markstein: RN result)
    float rem2 = fmaf(-b, y, a);              // exact residual
    y = fmaf(rem2, r, y);                     // fixup 2 (idempotent safety)
    return y;
}

// Packed 2-wide tanh for the hot loop: SAME per-component IEEE ops with
// div_exact in place of '/' (bit-identical quotient per the analysis above).
__device__ __forceinline__ v2f xla_tanh2(v2f x) {
#pragma clang fp contract(off)
    const float C = 7.99881172180175781f;
    v2f xc = __builtin_elementwise_min(__builtin_elementwise_max(x, splat2(-C)), splat2(C));
    v2f x2 = xc * xc;
    v2f p = splat2(-2.76076847742355e-16f);
    p = __builtin_elementwise_fma(p, x2, splat2(2.00018790482477e-13f));
    p = __builtin_elementwise_fma(p, x2, splat2(-8.60467152213735e-11f));
    p = __builtin_elementwise_fma(p, x2, splat2(5.12229709037114e-08f));
    p = __builtin_elementwise_fma(p, x2, splat2(1.48572235717979e-05f));
    p = __builtin_elementwise_fma(p, x2, splat2(6.37261928875436e-04f));
    p = __builtin_elementwise_fma(p, x2, splat2(4.89352455891786e-03f));
    v2f num = xc * p;
    v2f q = splat2(1.19825839466702e-06f);
    q = __builtin_elementwise_fma(q, x2, splat2(1.18534705686654e-04f));
    q = __builtin_elementwise_fma(q, x2, splat2(2.26843463243900e-03f));
    q = __builtin_elementwise_fma(q, x2, splat2(4.89352518554385e-03f));
    float rE = div_exact(num.x, q.x);        // == IEEE '/', interleavable
    float rI = div_exact(num.y, q.y);
    v2f r;
    r.x = (fabsf(x.x) < 0.0004f) ? x.x : rE;
    r.y = (fabsf(x.y) < 0.0004f) ? x.y : rI;
    return r;
}

// XLA CPU f32 exp (Cephes/Eigen pexp), FMA-contracted. [bitwise-verified]
__device__ __forceinline__ float xla_expf(float x) {
#pragma clang fp contract(off)
    float xc = fminf(fmaxf(x, -88.3762626647949f), 88.3762626647950f);
    float fx = floorf(fmaf(xc, 1.44269504088896341f, 0.5f));
    float r = fmaf(fx, -0.693359375f, xc);
    r = fmaf(fx, 2.12194440e-4f, r);
    float r2 = r * r;
    float y = 1.9875691500e-4f;
    y = fmaf(y, r, 1.3981999507e-3f);
    y = fmaf(y, r, 8.3334519073e-3f);
    y = fmaf(y, r, 4.1665795894e-2f);
    y = fmaf(y, r, 1.6666665459e-1f);
    y = fmaf(y, r, 5.0000001201e-1f);
    y = fmaf(y, r2, r);
    y = y + 1.0f;
    int n2 = (int)fx;
    float p2n = __int_as_float((n2 + 127) << 23);   // n==-127 -> +0.0
    return y * p2n;
}

// Shared per-element preamble (bitwise-identical everywhere).
__device__ __forceinline__ void preamble(float xv, const float* p,
                                         float& sim0, float& damp, float& omega) {
#pragma clang fp contract(off)
    float mu = p[10], e = p[11], k = p[12];
    float sgn  = (xv > 0.0f) ? 1.0f : ((xv < 0.0f) ? -1.0f : 0.0f);
    sim0 = fmaf(e, sgn, xv);                  // fadd(x, fmul(e,sgn)) fused
    float targ = (-k * sim0) * sim0;          // two plain muls
    damp  = xla_expf(targ);
    omega = xla_tanhf(mu * sim0);
}

// Full predicate (t != 1 and monolithic fallback). PROVEN lemma (round 9):
// 2*damp < |omega|*2^-26 with |D|<2 => fma(D,damp,omega)==omega every step.
__device__ __forceinline__ bool fast_omega(float damp, float omega) {
    return (2.0f * damp) < (fabsf(omega) * 0x1p-26f);
}

// t==1 cheap classification: slow iff |sim0| <= 0.21. PROVEN subset of the
// predicate above (22x margin at the boundary, grows like e^{500(s^2-0.0441)}).
// Slow-side routing is always correctness-neutral (loop returns omega).
__device__ __forceinline__ bool slow_t1(float xv, float e) {
#pragma clang fp contract(off)
    float sgn  = (xv > 0.0f) ? 1.0f : ((xv < 0.0f) ? -1.0f : 0.0f);
    float sim0 = fmaf(e, sgn, xv);
    return fabsf(sim0) <= 0.21f;
}

// 100-step loop, type-1 specialization (a1=b1=0, a4=1, xi=0), pk-packed.
// Per-component ops bitwise-identical to the round-6 verified scalar loop
// (div_exact == IEEE '/' per the Markstein analysis).
__device__ __forceinline__ float loop_t1(float sim0, float damp, float omega) {
#pragma clang fp contract(off)
    float E = 0.2f, I = 0.0f;
    float Dmax = -INFINITY;
    for (int s = 0; s < N_STEPS; ++s) {
        float tE = 5.0f * E;                   // round(a2*E)  (0*L unfolded)
        v2f mulc; mulc.x = -5.0f; mulc.y = -1.0f;
        v2f iv   = splat2(I);
        v2f addv; addv.x = tE;    addv.y = E;
        v2f u = __builtin_elementwise_fma(mulc, iv, addv);  // (uE, E-I)
        float sE = u.x + sim0;                 // plain fadd (a4==1 folded)
        v2f pre; pre.x = sE; pre.y = u.y;
        v2f args = splat2(5.0f) * pre;         // (argE, argI)
        v2f t = xla_tanh2(args);
        float D = t.x - t.y;                   // plain fsub
        Dmax = fmaxf(Dmax, D);
        E = t.x; I = t.y;
    }
    return fmaf(Dmax, damp, omega);            // == max_t fma(D_t,damp,omega)
}

// Generic-type loop (L feedback), proven scalar form (IEEE '/', untouched).
__device__ __forceinline__ float loop_gen(const float* p, float sim0,
                                          float damp, float omega) {
#pragma clang fp contract(off)
    float a1 = p[0], a2 = p[1], a3 = p[2], a4 = p[3];
    float b1 = p[4], b2 = p[5], b3 = p[6], b4 = p[7];
    float xiE = p[8], xiI = p[9], mu = p[10];
    float nb2 = -b2;
    float E = 0.2f, I = 0.0f, L = 0.2f;
    float m = -INFINITY;
    for (int s = 0; s < N_STEPS; ++s) {
        float tE = a2 * E;
        float uE = fmaf(a1, L, tE);
        uE = fmaf(-a3, I, uE);
        uE = fmaf(a4, sim0, uE);
        uE = uE - xiE;
        float argE = mu * uE;
        float tI = nb2 * E;
        float uI = fmaf(b1, L, tI);
        uI = fmaf(-b3, I, uI);
        uI = fmaf(b4, sim0, uI);
        uI = uI - xiI;
        float argI = mu * uI;
        float E1 = xla_tanhf(argE);
        float I1 = xla_tanhf(argI);
        float d = E1 - I1;
        L = fmaf(d, damp, omega);
        E = E1; I = I1;
        m = fmaxf(m, L);
    }
    return m;
}

// Classification shared by k_count / k_fill (must agree EXACTLY).
__device__ __forceinline__ bool classify_slow(float xv, int t, const float* p) {
    if (t == 1) return slow_t1(xv, p[11]);
    float sim0, damp, omega;
    preamble(xv, p, sim0, damp, omega);
    return !fast_omega(damp, omega);
}

// ---------------- kernels ----------------

// 1) per-block slow-lane count (ballot + popc, no atomics)
__global__ __launch_bounds__(256)
void k_count(const float* __restrict__ x, const int* __restrict__ osc_type,
             unsigned* __restrict__ bcount, int n)
{
    __shared__ unsigned wc[4];
    int i = blockIdx.x * 256 + threadIdx.x;
    int t = *osc_type;
    const float* p = PAR[t - 1];
    bool slow = (i < n) && classify_slow(x[i], t, p);
    unsigned long long mask = __ballot(slow);
    int lane = threadIdx.x & 63, wid = threadIdx.x >> 6;
    if (lane == 0) wc[wid] = (unsigned)__popcll(mask);
    __syncthreads();
    if (threadIdx.x == 0) bcount[blockIdx.x] = wc[0] + wc[1] + wc[2] + wc[3];
}

// 2) fill: self-scan bcount for this block's base; fast lanes -> out=omega;
//    slow lanes -> wl[base + local prefix]; last block writes bcount[NB]=total.
__global__ __launch_bounds__(256)
void k_fill(const float* __restrict__ x, const int* __restrict__ osc_type,
            float* __restrict__ out, unsigned* __restrict__ bcount,
            unsigned* __restrict__ wl, int n, int NB)
{
#pragma clang fp contract(off)
    __shared__ unsigned sums[256];
    __shared__ unsigned woff[4];
    int tid = threadIdx.x;
    int bid = blockIdx.x;

    // self-scan: base = sum of bcount[0..bid)
    unsigned s = 0;
    for (int j = tid; j < bid; j += 256) s += bcount[j];
    sums[tid] = s;
    __syncthreads();
    for (int off = 128; off > 0; off >>= 1) {
        if (tid < off) sums[tid] += sums[tid + off];
        __syncthreads();
    }
    unsigned bbase = sums[0];

    int i = bid * 256 + tid;
    bool active = (i < n);
    int t = *osc_type;
    const float* p = PAR[t - 1];
    float xv = active ? x[i] : 1.0e9f;          // 1e9 -> fast (and inactive)
    bool slow = active && classify_slow(xv, t, p);
    if (active && !slow) {
        // omega, computed exactly as in preamble
        float mu = p[10], e = p[11];
        float sgn  = (xv > 0.0f) ? 1.0f : ((xv < 0.0f) ? -1.0f : 0.0f);
        float sim0 = fmaf(e, sgn, xv);
        out[i] = xla_tanhf(mu * sim0);
    }
    unsigned long long mask = __ballot(slow);
    int lane = tid & 63, wid = tid >> 6;
    if (lane == 0) woff[wid] = (unsigned)__popcll(mask);
    __syncthreads();
    if (slow) {
        unsigned base = bbase;
        for (int w = 0; w < wid; ++w) base += woff[w];
        base += (unsigned)__popcll(mask & ((1ull << lane) - 1ull));
        wl[base] = (unsigned)i;
    }
    if (tid == 0 && bid == NB - 1)
        bcount[NB] = bbase + woff[0] + woff[1] + woff[2] + woff[3];
}

// 3) dense worklist: 1 element/thread (best issue efficiency), 64-thread
//    workgroups for finest CU balance, grid-stride for safety.
__global__ __launch_bounds__(64)
void k_process(const float* __restrict__ x, const int* __restrict__ osc_type,
               float* __restrict__ out, const unsigned* __restrict__ total_p,
               const unsigned* __restrict__ wl)
{
#pragma clang fp contract(off)
    unsigned total = *total_p;
    int t = *osc_type;
    const float* p = PAR[t - 1];
    unsigned stride = gridDim.x * 64u;
    for (unsigned tid = blockIdx.x * 64u + threadIdx.x; tid < total; tid += stride) {
        int i = (int)wl[tid];
        float sim0, damp, omega;
        preamble(x[i], p, sim0, damp, omega);
        out[i] = (t == 1) ? loop_t1(sim0, damp, omega)
                          : loop_gen(p, sim0, damp, omega);
    }
}

// Fallback: proven monolithic kernel (if ws too small).
__global__ __launch_bounds__(256)
void k_monolithic(const float* __restrict__ x, const int* __restrict__ osc_type,
                  float* __restrict__ out, int n)
{
#pragma clang fp contract(off)
    int i = blockIdx.x * 256 + threadIdx.x;
    if (i >= n) return;
    int t = *osc_type;
    const float* p = PAR[t - 1];
    float sim0, damp, omega;
    preamble(x[i], p, sim0, damp, omega);
    if (fast_omega(damp, omega)) { out[i] = omega; return; }
    out[i] = (t == 1) ? loop_t1(sim0, damp, omega)
                      : loop_gen(p, sim0, damp, omega);
}

extern "C" void kernel_launch(void* const* d_in, const int* in_sizes, int n_in,
                              void* d_out, int out_size, void* d_ws, size_t ws_size,
                              hipStream_t stream) {
    const float* x        = (const float*)d_in[0];
    const int*   osc_type = (const int*)d_in[1];
    float*       out      = (float*)d_out;
    int n = in_sizes[0];
    int NB = (n + 255) / 256;

    size_t needed = ((size_t)NB + 1 + (size_t)n) * sizeof(unsigned);
    if (ws_size >= needed) {
        unsigned* bcount = (unsigned*)d_ws;      // NB+1 entries ([NB] = total)
        unsigned* wl     = bcount + NB + 1;      // n entries
        k_count  <<<NB, 256, 0, stream>>>(x, osc_type, bcount, n);
        k_fill   <<<NB, 256, 0, stream>>>(x, osc_type, out, bcount, wl, n, NB);
        k_process<<<4096, 64, 0, stream>>>(x, osc_type, out, bcount + NB, wl);
    } else {
        k_monolithic<<<NB, 256, 0, stream>>>(x, osc_type, out, n);
    }
}